// Round 1
// baseline (3123.141 us; speedup 1.0000x reference)
//
#include <hip/hip_runtime.h>

// DeepPoly backsubstitution, fp32, MI355X.
// 16 sequential "step" GEMM kernels (ping-pong in d_ws) + init transpose + final reduce.
// Step fuses 4 matmuls: xl' = max(xl,0)@A_lo + min(xl,0)@A_up ; xu' = max(xu,0)@A_up + min(xu,0)@A_lo
// and the bias matvec (bl += max(xl,0)@c_lo + min(xl,0)@c_up, etc.) into the j==0 block column.

#define DD 1024
#define LL 16
#define BM 64
#define BN 64
#define BK 16
#define TM 4
#define TN 4
#define XPAD 4                    // keeps 16B row alignment AND breaks write bank conflicts to ~2-way
#define XSTRIDE (BM + XPAD)       // 68 floats = 272 B, 16B-aligned rows

struct alignas(16) StepSmem {
  float xl[2][BK][XSTRIDE];   // k-major (transposed) X tiles: [k][m]
  float xu[2][BK][XSTRIDE];
  float alo[2][BK][BN];       // natural [k][j]
  float aup[2][BK][BN];
  float clo[2][BK];
  float cup[2][BK];
  float bred[8][64];          // bias cross-thread reduce: [quarter | 4+quarter][row]
};

__global__ __launch_bounds__(256)
void bs_step(const float* __restrict__ Xl, const float* __restrict__ Xu,
             float* __restrict__ Yl, float* __restrict__ Yu,
             const float* __restrict__ Alo, const float* __restrict__ Aup,
             const float* __restrict__ Clo, const float* __restrict__ Cup,
             float* __restrict__ bl, float* __restrict__ bu)
{
  __shared__ StepSmem sm;
  const int tid = threadIdx.x;
  const int tx = tid & 15;          // output col group (j)
  const int ty = tid >> 4;          // output row group (i)
  const int i0 = blockIdx.y * BM;
  const int j0 = blockIdx.x * BN;
  const bool doBias = (blockIdx.x == 0);

  // staging index maps
  const int xrow = tid >> 2;        // 0..63  (m)
  const int xseg = tid & 3;         // 0..3   (k segment of 4)
  const int arow = tid >> 4;        // 0..15  (k)
  const int acol = (tid & 15) * 4;  // 0..60  (j)
  // bias partial maps
  const int brow = tid & 63;        // row within tile
  const int bq   = tid >> 6;        // k-quarter (4 k's each)

  float accl[TM][TN] = {};
  float accu[TM][TN] = {};
  float blp = 0.f, bup = 0.f;

  float4 rxl, rxu, ral, rau;
  float  rc = 0.f;

  auto load_panel = [&](int kp) {
    rxl = *(const float4*)&Xl[(size_t)(i0 + xrow) * DD + kp + xseg * 4];
    rxu = *(const float4*)&Xu[(size_t)(i0 + xrow) * DD + kp + xseg * 4];
    ral = *(const float4*)&Alo[(size_t)(kp + arow) * DD + j0 + acol];
    rau = *(const float4*)&Aup[(size_t)(kp + arow) * DD + j0 + acol];
    if (tid < 32) rc = (tid < 16) ? Clo[kp + tid] : Cup[kp + tid - 16];
  };
  auto store_panel = [&](int b) {
    const float* pxl = (const float*)&rxl;
    const float* pxu = (const float*)&rxu;
#pragma unroll
    for (int s2 = 0; s2 < 4; ++s2) {
      sm.xl[b][xseg * 4 + s2][xrow] = pxl[s2];
      sm.xu[b][xseg * 4 + s2][xrow] = pxu[s2];
    }
    *(float4*)&sm.alo[b][arow][acol] = ral;
    *(float4*)&sm.aup[b][arow][acol] = rau;
    if (tid < 16)      sm.clo[b][tid] = rc;
    else if (tid < 32) sm.cup[b][tid - 16] = rc;
  };

  load_panel(0);
  store_panel(0);
  __syncthreads();

  constexpr int NP = DD / BK;   // 64 panels
  for (int p = 0; p < NP; ++p) {
    const int buf = p & 1;
    const bool more = (p + 1 < NP);
    if (more) load_panel((p + 1) * BK);   // issue global loads early; wait happens at store

#pragma unroll 4
    for (int k = 0; k < BK; ++k) {
      const float4 xl4 = *(const float4*)&sm.xl[buf][k][ty * TM]; // broadcast across tx
      const float4 xu4 = *(const float4*)&sm.xu[buf][k][ty * TM];
      const float4 al4 = *(const float4*)&sm.alo[buf][k][tx * TN]; // 2-way (free) across wave
      const float4 au4 = *(const float4*)&sm.aup[buf][k][tx * TN];
      const float xlv[TM] = {xl4.x, xl4.y, xl4.z, xl4.w};
      const float xuv[TM] = {xu4.x, xu4.y, xu4.z, xu4.w};
      const float alv[TN] = {al4.x, al4.y, al4.z, al4.w};
      const float auv[TN] = {au4.x, au4.y, au4.z, au4.w};
#pragma unroll
      for (int m = 0; m < TM; ++m) {
        const float pl = fmaxf(xlv[m], 0.f), nl = fminf(xlv[m], 0.f);
        const float pu = fmaxf(xuv[m], 0.f), nu = fminf(xuv[m], 0.f);
#pragma unroll
        for (int n = 0; n < TN; ++n) {
          accl[m][n] = fmaf(pl, alv[n], fmaf(nl, auv[n], accl[m][n]));
          accu[m][n] = fmaf(pu, auv[n], fmaf(nu, alv[n], accu[m][n]));
        }
      }
    }

    if (doBias) {
      // bias matvec partial from the staged (old) X tiles
#pragma unroll
      for (int kk = 0; kk < 4; ++kk) {
        const int k = bq * 4 + kk;
        const float xlv = sm.xl[buf][k][brow];
        const float xuv = sm.xu[buf][k][brow];
        const float cl = sm.clo[buf][k], cu = sm.cup[buf][k];
        blp += fmaxf(xlv, 0.f) * cl + fminf(xlv, 0.f) * cu;
        bup += fmaxf(xuv, 0.f) * cu + fminf(xuv, 0.f) * cl;
      }
    }

    if (more) store_panel(buf ^ 1);  // writes other buffer; prev reads of it ended before last barrier
    __syncthreads();
  }

  // epilogue: coalesced float4 stores
#pragma unroll
  for (int m = 0; m < TM; ++m) {
    *(float4*)&Yl[(size_t)(i0 + ty * TM + m) * DD + j0 + tx * TN] =
        make_float4(accl[m][0], accl[m][1], accl[m][2], accl[m][3]);
    *(float4*)&Yu[(size_t)(i0 + ty * TM + m) * DD + j0 + tx * TN] =
        make_float4(accu[m][0], accu[m][1], accu[m][2], accu[m][3]);
  }

  if (doBias) {
    sm.bred[bq][brow]     = blp;
    sm.bred[4 + bq][brow] = bup;
    __syncthreads();
    if (tid < 64) {
      const int i = i0 + tid;
      bl[i] += sm.bred[0][tid] + sm.bred[1][tid] + sm.bred[2][tid] + sm.bred[3][tid];
      bu[i] += sm.bred[4][tid] + sm.bred[5][tid] + sm.bred[6][tid] + sm.bred[7][tid];
    }
  }
}

// W (D x D) -> W^T written to both xl0 and xu0
__global__ __launch_bounds__(256)
void bs_transpose_init(const float* __restrict__ W,
                       float* __restrict__ xl, float* __restrict__ xu)
{
  __shared__ float tile[32][33];
  const int x  = blockIdx.x * 32 + threadIdx.x;
  const int y0 = blockIdx.y * 32 + threadIdx.y;
#pragma unroll
  for (int r = 0; r < 32; r += 8)
    tile[threadIdx.y + r][threadIdx.x] = W[(size_t)(y0 + r) * DD + x];
  __syncthreads();
  const int xo  = blockIdx.y * 32 + threadIdx.x;
  const int yo0 = blockIdx.x * 32 + threadIdx.y;
#pragma unroll
  for (int r = 0; r < 32; r += 8) {
    const float v = tile[threadIdx.x][threadIdx.y + r];
    xl[(size_t)(yo0 + r) * DD + xo] = v;
    xu[(size_t)(yo0 + r) * DD + xo] = v;
  }
}

// lowers[i] = sum_j max(xl,0)*lo + min(xl,0)*up + bl[i];  uppers analogous. out = [lowers | uppers]
__global__ __launch_bounds__(256)
void bs_final(const float* __restrict__ Xl, const float* __restrict__ Xu,
              const float* __restrict__ bl, const float* __restrict__ bu,
              const float* __restrict__ inLo, const float* __restrict__ inUp,
              float* __restrict__ out)
{
  __shared__ float red[2][4];
  const int i = blockIdx.x;
  const int tid = threadIdx.x;
  const float4 xl4 = *(const float4*)&Xl[(size_t)i * DD + tid * 4];
  const float4 xu4 = *(const float4*)&Xu[(size_t)i * DD + tid * 4];
  const float4 lo4 = *(const float4*)&inLo[tid * 4];
  const float4 up4 = *(const float4*)&inUp[tid * 4];
  const float xlv[4] = {xl4.x, xl4.y, xl4.z, xl4.w};
  const float xuv[4] = {xu4.x, xu4.y, xu4.z, xu4.w};
  const float lov[4] = {lo4.x, lo4.y, lo4.z, lo4.w};
  const float upv[4] = {up4.x, up4.y, up4.z, up4.w};
  float sl = 0.f, su = 0.f;
#pragma unroll
  for (int c = 0; c < 4; ++c) {
    sl += fmaxf(xlv[c], 0.f) * lov[c] + fminf(xlv[c], 0.f) * upv[c];
    su += fmaxf(xuv[c], 0.f) * upv[c] + fminf(xuv[c], 0.f) * lov[c];
  }
#pragma unroll
  for (int off = 32; off > 0; off >>= 1) {
    sl += __shfl_down(sl, off, 64);
    su += __shfl_down(su, off, 64);
  }
  if ((tid & 63) == 0) { red[0][tid >> 6] = sl; red[1][tid >> 6] = su; }
  __syncthreads();
  if (tid == 0) {
    out[i]      = red[0][0] + red[0][1] + red[0][2] + red[0][3] + bl[i];
    out[DD + i] = red[1][0] + red[1][1] + red[1][2] + red[1][3] + bu[i];
  }
}

extern "C" void kernel_launch(void* const* d_in, const int* in_sizes, int n_in,
                              void* d_out, int out_size, void* d_ws, size_t ws_size,
                              hipStream_t stream)
{
  const float* W      = (const float*)d_in[0];
  const float* biases = (const float*)d_in[1];
  const float* AloAll = (const float*)d_in[2];   // (L, D, D)
  const float* AupAll = (const float*)d_in[3];
  const float* CloAll = (const float*)d_in[4];   // (L, D, 1)
  const float* CupAll = (const float*)d_in[5];
  const float* inLo   = (const float*)d_in[6];
  const float* inUp   = (const float*)d_in[7];
  float* out = (float*)d_out;

  float* ws  = (float*)d_ws;
  float* XA  = ws;
  float* XuA = ws + (size_t)DD * DD;
  float* XB  = ws + 2ull * DD * DD;
  float* XuB = ws + 3ull * DD * DD;
  float* bl  = ws + 4ull * DD * DD;
  float* bu  = bl + DD;

  bs_transpose_init<<<dim3(DD / 32, DD / 32), dim3(32, 8), 0, stream>>>(W, XA, XuA);
  hipMemcpyAsync(bl, biases, DD * sizeof(float), hipMemcpyDeviceToDevice, stream);
  hipMemcpyAsync(bu, biases, DD * sizeof(float), hipMemcpyDeviceToDevice, stream);

  const float* xi  = XA;  const float* xui = XuA;
  float*       xo  = XB;  float*       xuo = XuB;
  for (int l = 0; l < LL; ++l) {
    bs_step<<<dim3(DD / BN, DD / BM), 256, 0, stream>>>(
        xi, xui, xo, xuo,
        AloAll + (size_t)l * DD * DD, AupAll + (size_t)l * DD * DD,
        CloAll + (size_t)l * DD,      CupAll + (size_t)l * DD,
        bl, bu);
    const float* txi = xi; const float* txui = xui;
    xi = xo; xui = xuo;
    xo = (float*)txi; xuo = (float*)txui;
  }

  bs_final<<<DD, 256, 0, stream>>>(xi, xui, bl, bu, inLo, inUp, out);
}

// Round 3
// 1160.583 us; speedup vs baseline: 2.6910x; 2.6910x over previous
//
#include <hip/hip_runtime.h>

// DeepPoly backsubstitution, MI355X. Round 2: f16 MFMA with exact 2-term split.
//
// Per step (4 sign-split matmuls, D=1024):
//   xl' = pl@A_lo + nl@A_up ; xu' = pu@A_up + nu@A_lo   (pl=max(xl,0), nl=min(xl,0), ...)
// Each fp32 operand is split  v = v1 + (1/2048)*v2'  with v1 = f16(v), v2' = f16((v-v1)*2048).
// Products kept: v1*w1 (scale 1), v1*w2' and v2'*w1 (scale 1/2048); dropped term ~2^-22 rel.
// K-concat: each output = one GEMM with K = 6*1024 (segment table of plane pointers);
// scaled segments come FIRST, acc *= 1/2048 once at the group boundary.
// Split-K x4 and z in {lo,up}: grid 8x8x8 = 512 blocks (2/CU). Partials reduced in the
// convert kernel, which also re-clamps, re-splits, and accumulates the bias matvec.

#define DD 1024
#define LL 16

typedef _Float16 f16x8 __attribute__((ext_vector_type(8)));
typedef _Float16 f16x4 __attribute__((ext_vector_type(4)));
typedef float f32x4 __attribute__((ext_vector_type(4)));

__device__ __forceinline__ void gload16(const void* gsrc, void* ldst) {
  __builtin_amdgcn_global_load_lds(
      (const __attribute__((address_space(1))) unsigned int*)gsrc,
      (__attribute__((address_space(3))) unsigned int*)ldst, 16, 0, 0);
}

struct GemmTabs {
  const _Float16* xs[2][6];
  const _Float16* as[2][6];
};

// ---------------- MFMA GEMM step: out[slab] = (X-planes @ A-planes) partials ----------------
__global__ __launch_bounds__(256)
void gemm_step(GemmTabs tabs, float* __restrict__ part)
{
  // frag-contiguous LDS: one fragment = 64 lanes x 16 B = 1024 B, staged by ONE
  // global_load_lds issue (wave-uniform dest); ds_read_b128 at base+lane*16 -> conflict-free.
  __shared__ _Float16 smX[2][16][512];   // [buf][fragid = mf*2+kc][512 halfs]
  __shared__ _Float16 smA[2][16][512];   // [buf][fragid = nf*2+kc][...]

  const int tid  = threadIdx.x;
  const int w    = tid >> 6;
  const int lane = tid & 63;
  const int ln15 = lane & 15;
  const int lhi  = lane >> 4;

  const int j0 = blockIdx.x * 128;       // n tile
  const int i0 = blockIdx.y * 128;       // m tile
  const int lu    = blockIdx.z >> 2;
  const int split = blockIdx.z & 3;

  const _Float16* const* xtab = tabs.xs[lu];
  const _Float16* const* atab = tabs.as[lu];

  const int wm = w >> 1, wn = w & 1;     // 2x2 waves, each 64x64

  f32x4 acc[4][4];
#pragma unroll
  for (int a = 0; a < 4; ++a)
#pragma unroll
    for (int b = 0; b < 4; ++b) acc[a][b] = (f32x4){0.f, 0.f, 0.f, 0.f};

  constexpr int NIT = 24;                           // 1536 K per split
  const int b_it = (4096 - split * 1536) >> 6;      // scale-group boundary iter

  auto stage = [&](int buf, int it) {
    const int gk   = split * 1536 + it * 64;
    const int seg  = gk >> 10;
    const int koff = gk & 1023;
    const _Float16* xp = xtab[seg];
    const _Float16* ap = atab[seg];
#pragma unroll
    for (int r = 0; r < 4; ++r) {
      const int f  = r * 4 + w;          // fragment id, wave-uniform
      const int rf = f >> 1;
      const int kc = f & 1;
      const int kcol = koff + kc * 32 + lhi * 8;
      gload16(xp + (size_t)(i0 + rf * 16 + ln15) * DD + kcol, &smX[buf][f][0]);
      gload16(ap + (size_t)(j0 + rf * 16 + ln15) * DD + kcol, &smA[buf][f][0]);
    }
  };

  stage(0, 0);
  __syncthreads();

  int buf = 0;
  for (int it = 0; it < NIT; ++it) {
    if (it + 1 < NIT) stage(buf ^ 1, it + 1);
    if (it == b_it) {                    // scaled group done: acc *= 2^-11
#pragma unroll
      for (int a = 0; a < 4; ++a)
#pragma unroll
        for (int b = 0; b < 4; ++b) acc[a][b] *= (1.f / 2048.f);
    }
#pragma unroll
    for (int kc = 0; kc < 2; ++kc) {
      f16x8 xf[4], af[4];
#pragma unroll
      for (int mi = 0; mi < 4; ++mi)
        xf[mi] = *(const f16x8*)&smX[buf][(wm * 4 + mi) * 2 + kc][lane * 8];
#pragma unroll
      for (int ni = 0; ni < 4; ++ni)
        af[ni] = *(const f16x8*)&smA[buf][(wn * 4 + ni) * 2 + kc][lane * 8];
#pragma unroll
      for (int mi = 0; mi < 4; ++mi)
#pragma unroll
        for (int ni = 0; ni < 4; ++ni)
          acc[mi][ni] = __builtin_amdgcn_mfma_f32_16x16x32_f16(xf[mi], af[ni], acc[mi][ni], 0, 0, 0);
    }
    __syncthreads();
    buf ^= 1;
  }

  const float eps = (b_it >= NIT) ? (1.f / 2048.f) : 1.f;  // all-scaled splits
  float* outp = part + ((size_t)(split * 2 + lu) << 20);
#pragma unroll
  for (int mi = 0; mi < 4; ++mi) {
    const int r0 = i0 + wm * 64 + mi * 16 + lhi * 4;       // C: row=(lane>>4)*4+reg
#pragma unroll
    for (int ni = 0; ni < 4; ++ni) {
      const int c = j0 + wn * 64 + ni * 16 + ln15;         // C: col=lane&15
#pragma unroll
      for (int e = 0; e < 4; ++e)
        outp[(size_t)(r0 + e) * DD + c] = acc[mi][ni][e] * eps;
    }
  }
}

// -------- convert: reduce split-K partials, clamp, 2-term split to planes, bias matvec --------
__global__ __launch_bounds__(256)
void convert_split(int direct,
                   const float* __restrict__ xt, const float* __restrict__ part,
                   const float* __restrict__ cl, const float* __restrict__ cu,
                   _Float16* __restrict__ pl1, _Float16* __restrict__ pl2,
                   _Float16* __restrict__ nl1, _Float16* __restrict__ nl2,
                   _Float16* __restrict__ pu1, _Float16* __restrict__ pu2,
                   _Float16* __restrict__ nu1, _Float16* __restrict__ nu2,
                   float* __restrict__ bl, float* __restrict__ bu)
{
  const int i = blockIdx.x;
  const int t = threadIdx.x;
  const int k = t * 4;
  const size_t off = (size_t)i * DD + k;

  float Yl[4], Yu[4];
  if (direct) {
    const float4 y = *(const float4*)&xt[off];
    Yl[0] = Yu[0] = y.x; Yl[1] = Yu[1] = y.y; Yl[2] = Yu[2] = y.z; Yl[3] = Yu[3] = y.w;
  } else {
#pragma unroll
    for (int e = 0; e < 4; ++e) { Yl[e] = 0.f; Yu[e] = 0.f; }
#pragma unroll
    for (int s = 0; s < 4; ++s) {
      const float4 a = *(const float4*)&part[((size_t)(s * 2 + 0) << 20) + off];
      const float4 b = *(const float4*)&part[((size_t)(s * 2 + 1) << 20) + off];
      Yl[0] += a.x; Yl[1] += a.y; Yl[2] += a.z; Yl[3] += a.w;
      Yu[0] += b.x; Yu[1] += b.y; Yu[2] += b.z; Yu[3] += b.w;
    }
  }

  const float4 c4l = *(const float4*)&cl[k];
  const float4 c4u = *(const float4*)&cu[k];
  const float Cl[4] = {c4l.x, c4l.y, c4l.z, c4l.w};
  const float Cu[4] = {c4u.x, c4u.y, c4u.z, c4u.w};

  f16x4 o_pl1, o_pl2, o_nl1, o_nl2, o_pu1, o_pu2, o_nu1, o_nu2;
  float blp = 0.f, bup = 0.f;
#pragma unroll
  for (int e = 0; e < 4; ++e) {
    const float pl = fmaxf(Yl[e], 0.f), nl = fminf(Yl[e], 0.f);
    const float pu = fmaxf(Yu[e], 0.f), nu = fminf(Yu[e], 0.f);
    blp += pl * Cl[e] + nl * Cu[e];
    bup += pu * Cu[e] + nu * Cl[e];
    _Float16 h;
    h = (_Float16)pl; o_pl1[e] = h; o_pl2[e] = (_Float16)((pl - (float)h) * 2048.f);
    h = (_Float16)nl; o_nl1[e] = h; o_nl2[e] = (_Float16)((nl - (float)h) * 2048.f);
    h = (_Float16)pu; o_pu1[e] = h; o_pu2[e] = (_Float16)((pu - (float)h) * 2048.f);
    h = (_Float16)nu; o_nu1[e] = h; o_nu2[e] = (_Float16)((nu - (float)h) * 2048.f);
  }
  *(f16x4*)&pl1[off] = o_pl1;  *(f16x4*)&pl2[off] = o_pl2;
  *(f16x4*)&nl1[off] = o_nl1;  *(f16x4*)&nl2[off] = o_nl2;
  *(f16x4*)&pu1[off] = o_pu1;  *(f16x4*)&pu2[off] = o_pu2;
  *(f16x4*)&nu1[off] = o_nu1;  *(f16x4*)&nu2[off] = o_nu2;

#pragma unroll
  for (int o = 32; o > 0; o >>= 1) {
    blp += __shfl_down(blp, o, 64);
    bup += __shfl_down(bup, o, 64);
  }
  __shared__ float red[2][4];
  if ((t & 63) == 0) { red[0][t >> 6] = blp; red[1][t >> 6] = bup; }
  __syncthreads();
  if (t == 0) {
    bl[i] += red[0][0] + red[0][1] + red[0][2] + red[0][3];
    bu[i] += red[1][0] + red[1][1] + red[1][2] + red[1][3];
  }
}

// -------- A-plane prep: fp32 [k][n] -> two f16 planes stored transposed [n][k] --------
__global__ __launch_bounds__(256)
void prep_a(const float* __restrict__ Alo, const float* __restrict__ Aup,
            _Float16* __restrict__ L1, _Float16* __restrict__ L2,
            _Float16* __restrict__ U1, _Float16* __restrict__ U2)
{
  __shared__ float tile[64][68];
  const int t = threadIdx.x;
  const int rid = t >> 4, cid = t & 15;
  const int k0 = blockIdx.x * 64, n0 = blockIdx.y * 64;
  const float* src = blockIdx.z ? Aup : Alo;
  _Float16* d1 = blockIdx.z ? U1 : L1;
  _Float16* d2 = blockIdx.z ? U2 : L2;
#pragma unroll
  for (int rr = 0; rr < 4; ++rr) {
    const int kk = rid * 4 + rr;
    *(float4*)&tile[kk][cid * 4] = *(const float4*)&src[(size_t)(k0 + kk) * DD + n0 + cid * 4];
  }
  __syncthreads();
#pragma unroll
  for (int rr = 0; rr < 4; ++rr) {
    const int n = rid * 4 + rr;
    f16x4 v1, v2;
#pragma unroll
    for (int e = 0; e < 4; ++e) {
      const float v = tile[cid * 4 + e][n];
      const _Float16 h = (_Float16)v;
      v1[e] = h;
      v2[e] = (_Float16)((v - (float)h) * 2048.f);
    }
    const size_t o = (size_t)(n0 + n) * DD + k0 + cid * 4;
    *(f16x4*)&d1[o] = v1;
    *(f16x4*)&d2[o] = v2;
  }
}

// -------- init: W -> W^T (fp32) --------
__global__ __launch_bounds__(256)
void transpose_w(const float* __restrict__ W, float* __restrict__ xt)
{
  __shared__ float tile[32][33];
  const int x  = blockIdx.x * 32 + threadIdx.x;
  const int y0 = blockIdx.y * 32 + threadIdx.y;
#pragma unroll
  for (int r = 0; r < 32; r += 8)
    tile[threadIdx.y + r][threadIdx.x] = W[(size_t)(y0 + r) * DD + x];
  __syncthreads();
  const int xo  = blockIdx.y * 32 + threadIdx.x;
  const int yo0 = blockIdx.x * 32 + threadIdx.y;
#pragma unroll
  for (int r = 0; r < 32; r += 8)
    xt[(size_t)(yo0 + r) * DD + xo] = tile[threadIdx.x][threadIdx.y + r];
}

// -------- final: reduce partials, concretize with input box --------
__global__ __launch_bounds__(256)
void bs_final2(const float* __restrict__ part,
               const float* __restrict__ bl, const float* __restrict__ bu,
               const float* __restrict__ inLo, const float* __restrict__ inUp,
               float* __restrict__ out)
{
  const int i = blockIdx.x;
  const int t = threadIdx.x;
  const int k = t * 4;
  const size_t off = (size_t)i * DD + k;
  float Xl[4] = {0.f, 0.f, 0.f, 0.f}, Xu[4] = {0.f, 0.f, 0.f, 0.f};
#pragma unroll
  for (int s = 0; s < 4; ++s) {
    const float4 a = *(const float4*)&part[((size_t)(s * 2 + 0) << 20) + off];
    const float4 b = *(const float4*)&part[((size_t)(s * 2 + 1) << 20) + off];
    Xl[0] += a.x; Xl[1] += a.y; Xl[2] += a.z; Xl[3] += a.w;
    Xu[0] += b.x; Xu[1] += b.y; Xu[2] += b.z; Xu[3] += b.w;
  }
  const float4 lo4 = *(const float4*)&inLo[k];
  const float4 up4 = *(const float4*)&inUp[k];
  const float Lo[4] = {lo4.x, lo4.y, lo4.z, lo4.w};
  const float Up[4] = {up4.x, up4.y, up4.z, up4.w};
  float sl = 0.f, su = 0.f;
#pragma unroll
  for (int e = 0; e < 4; ++e) {
    sl += fmaxf(Xl[e], 0.f) * Lo[e] + fminf(Xl[e], 0.f) * Up[e];
    su += fmaxf(Xu[e], 0.f) * Up[e] + fminf(Xu[e], 0.f) * Lo[e];
  }
#pragma unroll
  for (int o = 32; o > 0; o >>= 1) {
    sl += __shfl_down(sl, o, 64);
    su += __shfl_down(su, o, 64);
  }
  __shared__ float red[2][4];
  if ((t & 63) == 0) { red[0][t >> 6] = sl; red[1][t >> 6] = su; }
  __syncthreads();
  if (t == 0) {
    out[i]      = red[0][0] + red[0][1] + red[0][2] + red[0][3] + bl[i];
    out[DD + i] = red[1][0] + red[1][1] + red[1][2] + red[1][3] + bu[i];
  }
}

// ==================== fp32 fallback (round-1 baseline), used if ws too small ====================
#define BM 64
#define BN 64
#define BK 16
#define TM 4
#define TN 4
#define XPAD 4
#define XSTRIDE (BM + XPAD)

struct alignas(16) StepSmem {
  float xl[2][BK][XSTRIDE];
  float xu[2][BK][XSTRIDE];
  float alo[2][BK][BN];
  float aup[2][BK][BN];
  float clo[2][BK];
  float cup[2][BK];
  float bred[8][64];
};

__global__ __launch_bounds__(256)
void bs_step(const float* __restrict__ Xl, const float* __restrict__ Xu,
             float* __restrict__ Yl, float* __restrict__ Yu,
             const float* __restrict__ Alo, const float* __restrict__ Aup,
             const float* __restrict__ Clo, const float* __restrict__ Cup,
             float* __restrict__ bl, float* __restrict__ bu)
{
  __shared__ StepSmem sm;
  const int tid = threadIdx.x;
  const int tx = tid & 15;
  const int ty = tid >> 4;
  const int i0 = blockIdx.y * BM;
  const int j0 = blockIdx.x * BN;
  const bool doBias = (blockIdx.x == 0);
  const int xrow = tid >> 2;
  const int xseg = tid & 3;
  const int arow = tid >> 4;
  const int acol = (tid & 15) * 4;
  const int brow = tid & 63;
  const int bq   = tid >> 6;

  float accl[TM][TN] = {};
  float accu[TM][TN] = {};
  float blp = 0.f, bup = 0.f;
  float4 rxl, rxu, ral, rau;
  float  rc = 0.f;

  auto load_panel = [&](int kp) {
    rxl = *(const float4*)&Xl[(size_t)(i0 + xrow) * DD + kp + xseg * 4];
    rxu = *(const float4*)&Xu[(size_t)(i0 + xrow) * DD + kp + xseg * 4];
    ral = *(const float4*)&Alo[(size_t)(kp + arow) * DD + j0 + acol];
    rau = *(const float4*)&Aup[(size_t)(kp + arow) * DD + j0 + acol];
    if (tid < 32) rc = (tid < 16) ? Clo[kp + tid] : Cup[kp + tid - 16];
  };
  auto store_panel = [&](int b) {
    const float* pxl = (const float*)&rxl;
    const float* pxu = (const float*)&rxu;
#pragma unroll
    for (int s2 = 0; s2 < 4; ++s2) {
      sm.xl[b][xseg * 4 + s2][xrow] = pxl[s2];
      sm.xu[b][xseg * 4 + s2][xrow] = pxu[s2];
    }
    *(float4*)&sm.alo[b][arow][acol] = ral;
    *(float4*)&sm.aup[b][arow][acol] = rau;
    if (tid < 16)      sm.clo[b][tid] = rc;
    else if (tid < 32) sm.cup[b][tid - 16] = rc;
  };

  load_panel(0);
  store_panel(0);
  __syncthreads();

  constexpr int NP = DD / BK;
  for (int p = 0; p < NP; ++p) {
    const int buf = p & 1;
    const bool more = (p + 1 < NP);
    if (more) load_panel((p + 1) * BK);
#pragma unroll 4
    for (int k = 0; k < BK; ++k) {
      const float4 xl4 = *(const float4*)&sm.xl[buf][k][ty * TM];
      const float4 xu4 = *(const float4*)&sm.xu[buf][k][ty * TM];
      const float4 al4 = *(const float4*)&sm.alo[buf][k][tx * TN];
      const float4 au4 = *(const float4*)&sm.aup[buf][k][tx * TN];
      const float xlv[TM] = {xl4.x, xl4.y, xl4.z, xl4.w};
      const float xuv[TM] = {xu4.x, xu4.y, xu4.z, xu4.w};
      const float alv[TN] = {al4.x, al4.y, al4.z, al4.w};
      const float auv[TN] = {au4.x, au4.y, au4.z, au4.w};
#pragma unroll
      for (int m = 0; m < TM; ++m) {
        const float pl = fmaxf(xlv[m], 0.f), nl = fminf(xlv[m], 0.f);
        const float pu = fmaxf(xuv[m], 0.f), nu = fminf(xuv[m], 0.f);
#pragma unroll
        for (int n = 0; n < TN; ++n) {
          accl[m][n] = fmaf(pl, alv[n], fmaf(nl, auv[n], accl[m][n]));
          accu[m][n] = fmaf(pu, auv[n], fmaf(nu, alv[n], accu[m][n]));
        }
      }
    }
    if (doBias) {
#pragma unroll
      for (int kk = 0; kk < 4; ++kk) {
        const int k = bq * 4 + kk;
        const float xlv = sm.xl[buf][k][brow];
        const float xuv = sm.xu[buf][k][brow];
        const float cl = sm.clo[buf][k], cu = sm.cup[buf][k];
        blp += fmaxf(xlv, 0.f) * cl + fminf(xlv, 0.f) * cu;
        bup += fmaxf(xuv, 0.f) * cu + fminf(xuv, 0.f) * cl;
      }
    }
    if (more) store_panel(buf ^ 1);
    __syncthreads();
  }

#pragma unroll
  for (int m = 0; m < TM; ++m) {
    *(float4*)&Yl[(size_t)(i0 + ty * TM + m) * DD + j0 + tx * TN] =
        make_float4(accl[m][0], accl[m][1], accl[m][2], accl[m][3]);
    *(float4*)&Yu[(size_t)(i0 + ty * TM + m) * DD + j0 + tx * TN] =
        make_float4(accu[m][0], accu[m][1], accu[m][2], accu[m][3]);
  }
  if (doBias) {
    sm.bred[bq][brow]     = blp;
    sm.bred[4 + bq][brow] = bup;
    __syncthreads();
    if (tid < 64) {
      const int i = i0 + tid;
      bl[i] += sm.bred[0][tid] + sm.bred[1][tid] + sm.bred[2][tid] + sm.bred[3][tid];
      bu[i] += sm.bred[4][tid] + sm.bred[5][tid] + sm.bred[6][tid] + sm.bred[7][tid];
    }
  }
}

__global__ __launch_bounds__(256)
void bs_transpose_init(const float* __restrict__ W,
                       float* __restrict__ xl, float* __restrict__ xu)
{
  __shared__ float tile[32][33];
  const int x  = blockIdx.x * 32 + threadIdx.x;
  const int y0 = blockIdx.y * 32 + threadIdx.y;
#pragma unroll
  for (int r = 0; r < 32; r += 8)
    tile[threadIdx.y + r][threadIdx.x] = W[(size_t)(y0 + r) * DD + x];
  __syncthreads();
  const int xo  = blockIdx.y * 32 + threadIdx.x;
  const int yo0 = blockIdx.x * 32 + threadIdx.y;
#pragma unroll
  for (int r = 0; r < 32; r += 8) {
    const float v = tile[threadIdx.x][threadIdx.y + r];
    xl[(size_t)(yo0 + r) * DD + xo] = v;
    xu[(size_t)(yo0 + r) * DD + xo] = v;
  }
}

__global__ __launch_bounds__(256)
void bs_final(const float* __restrict__ Xl, const float* __restrict__ Xu,
              const float* __restrict__ bl, const float* __restrict__ bu,
              const float* __restrict__ inLo, const float* __restrict__ inUp,
              float* __restrict__ out)
{
  __shared__ float red[2][4];
  const int i = blockIdx.x;
  const int tid = threadIdx.x;
  const float4 xl4 = *(const float4*)&Xl[(size_t)i * DD + tid * 4];
  const float4 xu4 = *(const float4*)&Xu[(size_t)i * DD + tid * 4];
  const float4 lo4 = *(const float4*)&inLo[tid * 4];
  const float4 up4 = *(const float4*)&inUp[tid * 4];
  const float xlv[4] = {xl4.x, xl4.y, xl4.z, xl4.w};
  const float xuv[4] = {xu4.x, xu4.y, xu4.z, xu4.w};
  const float lov[4] = {lo4.x, lo4.y, lo4.z, lo4.w};
  const float upv[4] = {up4.x, up4.y, up4.z, up4.w};
  float sl = 0.f, su = 0.f;
#pragma unroll
  for (int c = 0; c < 4; ++c) {
    sl += fmaxf(xlv[c], 0.f) * lov[c] + fminf(xlv[c], 0.f) * upv[c];
    su += fmaxf(xuv[c], 0.f) * upv[c] + fminf(xuv[c], 0.f) * lov[c];
  }
#pragma unroll
  for (int off = 32; off > 0; off >>= 1) {
    sl += __shfl_down(sl, off, 64);
    su += __shfl_down(su, off, 64);
  }
  if ((tid & 63) == 0) { red[0][tid >> 6] = sl; red[1][tid >> 6] = su; }
  __syncthreads();
  if (tid == 0) {
    out[i]      = red[0][0] + red[0][1] + red[0][2] + red[0][3] + bl[i];
    out[DD + i] = red[1][0] + red[1][1] + red[1][2] + red[1][3] + bu[i];
  }
}

// ==================== host ====================
extern "C" void kernel_launch(void* const* d_in, const int* in_sizes, int n_in,
                              void* d_out, int out_size, void* d_ws, size_t ws_size,
                              hipStream_t stream)
{
  const float* W      = (const float*)d_in[0];
  const float* biases = (const float*)d_in[1];
  const float* AloAll = (const float*)d_in[2];
  const float* AupAll = (const float*)d_in[3];
  const float* CloAll = (const float*)d_in[4];
  const float* CupAll = (const float*)d_in[5];
  const float* inLo   = (const float*)d_in[6];
  const float* inUp   = (const float*)d_in[7];
  float* out = (float*)d_out;

  const size_t NEED = (60ull << 20) + 8192;
  if (ws_size < NEED) {
    // ---------- fp32 fallback (round-1) ----------
    float* ws  = (float*)d_ws;
    float* XA  = ws;
    float* XuA = ws + (size_t)DD * DD;
    float* XB  = ws + 2ull * DD * DD;
    float* XuB = ws + 3ull * DD * DD;
    float* bl  = ws + 4ull * DD * DD;
    float* bu  = bl + DD;
    bs_transpose_init<<<dim3(DD / 32, DD / 32), dim3(32, 8), 0, stream>>>(W, XA, XuA);
    hipMemcpyAsync(bl, biases, DD * sizeof(float), hipMemcpyDeviceToDevice, stream);
    hipMemcpyAsync(bu, biases, DD * sizeof(float), hipMemcpyDeviceToDevice, stream);
    const float* xi  = XA;  const float* xui = XuA;
    float*       xo  = XB;  float*       xuo = XuB;
    for (int l = 0; l < LL; ++l) {
      bs_step<<<dim3(DD / BN, DD / BM), 256, 0, stream>>>(
          xi, xui, xo, xuo,
          AloAll + (size_t)l * DD * DD, AupAll + (size_t)l * DD * DD,
          CloAll + (size_t)l * DD,      CupAll + (size_t)l * DD, bl, bu);
      const float* txi = xi; const float* txui = xui;
      xi = xo; xui = xuo;
      xo = (float*)txi; xuo = (float*)txui;
    }
    bs_final<<<DD, 256, 0, stream>>>(xi, xui, bl, bu, inLo, inUp, out);
    return;
  }

  // ---------- f16-split MFMA path ----------
  char* ws = (char*)d_ws;
  float*     part = (float*)ws;                          // 8 slabs x 4 MB = 32 MB
  _Float16*  xpl  = (_Float16*)(ws + (32ull << 20));     // 8 X planes x 2 MB
  _Float16*  apl  = (_Float16*)(ws + (48ull << 20));     // 4 A planes x 2 MB
  float*     XT   = (float*)(ws + (56ull << 20));        // 4 MB
  float*     bl   = (float*)(ws + (60ull << 20));
  float*     bu   = bl + DD;

  auto P = [&](int idx) { return xpl + (size_t)idx * (1u << 20); };
  _Float16 *pl1 = P(0), *pl2 = P(1), *nl1 = P(2), *nl2 = P(3);
  _Float16 *pu1 = P(4), *pu2 = P(5), *nu1 = P(6), *nu2 = P(7);
  _Float16 *AL1 = apl, *AL2 = apl + (1u << 20), *AU1 = apl + (2u << 20), *AU2 = apl + (3u << 20);

  GemmTabs tabs;
  // lu=0 (xl'): scaled group first: pl1*AL2', pl2'*AL1, nl1*AU2', nl2'*AU1 ; then pl1*AL1, nl1*AU1
  const _Float16* xs0[6] = {pl1, pl2, nl1, nl2, pl1, nl1};
  const _Float16* as0[6] = {AL2, AL1, AU2, AU1, AL1, AU1};
  // lu=1 (xu'): pu1*AU2', pu2'*AU1, nu1*AL2', nu2'*AL1 ; then pu1*AU1, nu1*AL1
  const _Float16* xs1[6] = {pu1, pu2, nu1, nu2, pu1, nu1};
  const _Float16* as1[6] = {AU2, AU1, AL2, AL1, AU1, AL1};
  for (int s = 0; s < 6; ++s) {
    tabs.xs[0][s] = xs0[s]; tabs.as[0][s] = as0[s];
    tabs.xs[1][s] = xs1[s]; tabs.as[1][s] = as1[s];
  }

  transpose_w<<<dim3(32, 32), dim3(32, 8), 0, stream>>>(W, XT);
  hipMemcpyAsync(bl, biases, DD * sizeof(float), hipMemcpyDeviceToDevice, stream);
  hipMemcpyAsync(bu, biases, DD * sizeof(float), hipMemcpyDeviceToDevice, stream);

  convert_split<<<DD, 256, 0, stream>>>(1, XT, part, CloAll, CupAll,
                                        pl1, pl2, nl1, nl2, pu1, pu2, nu1, nu2, bl, bu);
  for (int s = 0; s < LL; ++s) {
    prep_a<<<dim3(16, 16, 2), 256, 0, stream>>>(
        AloAll + (size_t)s * DD * DD, AupAll + (size_t)s * DD * DD, AL1, AL2, AU1, AU2);
    gemm_step<<<dim3(8, 8, 8), 256, 0, stream>>>(tabs, part);
    if (s < LL - 1)
      convert_split<<<DD, 256, 0, stream>>>(0, XT, part,
                                            CloAll + (size_t)(s + 1) * DD,
                                            CupAll + (size_t)(s + 1) * DD,
                                            pl1, pl2, nl1, nl2, pu1, pu2, nu1, nu2, bl, bu);
  }
  bs_final2<<<DD, 256, 0, stream>>>(part, bl, bu, inLo, inUp, out);
}

// Round 4
// 1132.793 us; speedup vs baseline: 2.7570x; 1.0245x over previous
//
#include <hip/hip_runtime.h>

// DeepPoly backsubstitution, MI355X. Round 4: f16-split MFMA + XCD-local z mapping
// + fused convert/prep kernel.
//
// gemm_step grid dim3(8,8,8); dispatcher round-robins linear block id across 8 XCDs,
// so we remap (lin&7) -> z=(lu,split): each XCD owns one z slice; its 64 co-resident
// blocks share a 256 KB live K-window in L2 (was: xcd=j0 -> 17 MB/XCD, 92 MB HBM fetch).

#define DD 1024
#define LL 16

typedef _Float16 f16x8 __attribute__((ext_vector_type(8)));
typedef _Float16 f16x4 __attribute__((ext_vector_type(4)));
typedef float f32x4 __attribute__((ext_vector_type(4)));

__device__ __forceinline__ void gload16(const void* gsrc, void* ldst) {
  __builtin_amdgcn_global_load_lds(
      (const __attribute__((address_space(1))) unsigned int*)gsrc,
      (__attribute__((address_space(3))) unsigned int*)ldst, 16, 0, 0);
}

struct GemmTabs {
  const _Float16* xs[2][6];
  const _Float16* as[2][6];
};

// ---------------- MFMA GEMM step: out[slab] = (X-planes @ A-planes) partials ----------------
__global__ __launch_bounds__(256)
void gemm_step(GemmTabs tabs, float* __restrict__ part)
{
  // frag-contiguous LDS: one fragment = 64 lanes x 16 B = 1024 B, staged by ONE
  // global_load_lds issue (wave-uniform dest); ds_read_b128 at base+lane*16 -> conflict-free.
  __shared__ _Float16 smX[2][16][512];   // [buf][fragid = mf*2+kc][512 halfs]
  __shared__ _Float16 smA[2][16][512];   // [buf][fragid = nf*2+kc][...]

  const int tid  = threadIdx.x;
  const int w    = tid >> 6;
  const int lane = tid & 63;
  const int ln15 = lane & 15;
  const int lhi  = lane >> 4;

  // XCD-local remap: xcd = lin&7 = z slice (lu,split); (i,j) tiles within the XCD.
  const int lin = blockIdx.x + (blockIdx.y << 3) + (blockIdx.z << 6);
  const int zz  = lin & 7;
  const int j0 = ((lin >> 3) & 7) * 128;  // n tile
  const int i0 = (lin >> 6) * 128;        // m tile
  const int lu    = zz >> 2;
  const int split = zz & 3;

  const _Float16* const* xtab = tabs.xs[lu];
  const _Float16* const* atab = tabs.as[lu];

  const int wm = w >> 1, wn = w & 1;     // 2x2 waves, each 64x64

  f32x4 acc[4][4];
#pragma unroll
  for (int a = 0; a < 4; ++a)
#pragma unroll
    for (int b = 0; b < 4; ++b) acc[a][b] = (f32x4){0.f, 0.f, 0.f, 0.f};

  constexpr int NIT = 24;                           // 1536 K per split
  const int b_it = (4096 - split * 1536) >> 6;      // scale-group boundary iter

  auto stage = [&](int buf, int it) {
    const int gk   = split * 1536 + it * 64;
    const int seg  = gk >> 10;
    const int koff = gk & 1023;
    const _Float16* xp = xtab[seg];
    const _Float16* ap = atab[seg];
#pragma unroll
    for (int r = 0; r < 4; ++r) {
      const int f  = r * 4 + w;          // fragment id, wave-uniform
      const int rf = f >> 1;
      const int kc = f & 1;
      const int kcol = koff + kc * 32 + lhi * 8;
      gload16(xp + (size_t)(i0 + rf * 16 + ln15) * DD + kcol, &smX[buf][f][0]);
      gload16(ap + (size_t)(j0 + rf * 16 + ln15) * DD + kcol, &smA[buf][f][0]);
    }
  };

  stage(0, 0);
  __syncthreads();

  int buf = 0;
  for (int it = 0; it < NIT; ++it) {
    if (it + 1 < NIT) stage(buf ^ 1, it + 1);
    if (it == b_it) {                    // scaled group done: acc *= 2^-11
#pragma unroll
      for (int a = 0; a < 4; ++a)
#pragma unroll
        for (int b = 0; b < 4; ++b) acc[a][b] *= (1.f / 2048.f);
    }
#pragma unroll
    for (int kc = 0; kc < 2; ++kc) {
      f16x8 xf[4], af[4];
#pragma unroll
      for (int mi = 0; mi < 4; ++mi)
        xf[mi] = *(const f16x8*)&smX[buf][(wm * 4 + mi) * 2 + kc][lane * 8];
#pragma unroll
      for (int ni = 0; ni < 4; ++ni)
        af[ni] = *(const f16x8*)&smA[buf][(wn * 4 + ni) * 2 + kc][lane * 8];
#pragma unroll
      for (int mi = 0; mi < 4; ++mi)
#pragma unroll
        for (int ni = 0; ni < 4; ++ni)
          acc[mi][ni] = __builtin_amdgcn_mfma_f32_16x16x32_f16(xf[mi], af[ni], acc[mi][ni], 0, 0, 0);
    }
    __syncthreads();
    buf ^= 1;
  }

  const float eps = (b_it >= NIT) ? (1.f / 2048.f) : 1.f;  // all-scaled splits
  float* outp = part + ((size_t)(split * 2 + lu) << 20);
#pragma unroll
  for (int mi = 0; mi < 4; ++mi) {
    const int r0 = i0 + wm * 64 + mi * 16 + lhi * 4;       // C: row=(lane>>4)*4+reg
#pragma unroll
    for (int ni = 0; ni < 4; ++ni) {
      const int c = j0 + wn * 64 + ni * 16 + ln15;         // C: col=lane&15
#pragma unroll
      for (int e = 0; e < 4; ++e)
        outp[(size_t)(r0 + e) * DD + c] = acc[mi][ni][e] * eps;
    }
  }
}

// -------- fused: [blocks 0..1023] convert (reduce partials, clamp, split, bias matvec)
//                 [blocks 1024..1535] prep next layer's A planes (fp32 [k][n] -> f16 [n][k] x2)
__global__ __launch_bounds__(256)
void convert_prep(int direct,
                  const float* __restrict__ xt, const float* __restrict__ part,
                  const float* __restrict__ cl, const float* __restrict__ cu,
                  _Float16* __restrict__ pl1, _Float16* __restrict__ pl2,
                  _Float16* __restrict__ nl1, _Float16* __restrict__ nl2,
                  _Float16* __restrict__ pu1, _Float16* __restrict__ pu2,
                  _Float16* __restrict__ nu1, _Float16* __restrict__ nu2,
                  float* __restrict__ bl, float* __restrict__ bu,
                  const float* __restrict__ AloN, const float* __restrict__ AupN,
                  _Float16* __restrict__ L1, _Float16* __restrict__ L2,
                  _Float16* __restrict__ U1, _Float16* __restrict__ U2)
{
  __shared__ float shmem[64][68];    // prep tile; convert reuses first 8 floats
  const int t = threadIdx.x;

  if (blockIdx.x < 1024) {
    // ---------------- convert path ----------------
    const int i = blockIdx.x;
    const int k = t * 4;
    const size_t off = (size_t)i * DD + k;

    float Yl[4], Yu[4];
    if (direct) {
      const float4 y = *(const float4*)&xt[off];
      Yl[0] = Yu[0] = y.x; Yl[1] = Yu[1] = y.y; Yl[2] = Yu[2] = y.z; Yl[3] = Yu[3] = y.w;
    } else {
#pragma unroll
      for (int e = 0; e < 4; ++e) { Yl[e] = 0.f; Yu[e] = 0.f; }
#pragma unroll
      for (int s = 0; s < 4; ++s) {
        const float4 a = *(const float4*)&part[((size_t)(s * 2 + 0) << 20) + off];
        const float4 b = *(const float4*)&part[((size_t)(s * 2 + 1) << 20) + off];
        Yl[0] += a.x; Yl[1] += a.y; Yl[2] += a.z; Yl[3] += a.w;
        Yu[0] += b.x; Yu[1] += b.y; Yu[2] += b.z; Yu[3] += b.w;
      }
    }

    const float4 c4l = *(const float4*)&cl[k];
    const float4 c4u = *(const float4*)&cu[k];
    const float Cl[4] = {c4l.x, c4l.y, c4l.z, c4l.w};
    const float Cu[4] = {c4u.x, c4u.y, c4u.z, c4u.w};

    f16x4 o_pl1, o_pl2, o_nl1, o_nl2, o_pu1, o_pu2, o_nu1, o_nu2;
    float blp = 0.f, bup = 0.f;
#pragma unroll
    for (int e = 0; e < 4; ++e) {
      const float pl = fmaxf(Yl[e], 0.f), nl = fminf(Yl[e], 0.f);
      const float pu = fmaxf(Yu[e], 0.f), nu = fminf(Yu[e], 0.f);
      blp += pl * Cl[e] + nl * Cu[e];
      bup += pu * Cu[e] + nu * Cl[e];
      _Float16 h;
      h = (_Float16)pl; o_pl1[e] = h; o_pl2[e] = (_Float16)((pl - (float)h) * 2048.f);
      h = (_Float16)nl; o_nl1[e] = h; o_nl2[e] = (_Float16)((nl - (float)h) * 2048.f);
      h = (_Float16)pu; o_pu1[e] = h; o_pu2[e] = (_Float16)((pu - (float)h) * 2048.f);
      h = (_Float16)nu; o_nu1[e] = h; o_nu2[e] = (_Float16)((nu - (float)h) * 2048.f);
    }
    *(f16x4*)&pl1[off] = o_pl1;  *(f16x4*)&pl2[off] = o_pl2;
    *(f16x4*)&nl1[off] = o_nl1;  *(f16x4*)&nl2[off] = o_nl2;
    *(f16x4*)&pu1[off] = o_pu1;  *(f16x4*)&pu2[off] = o_pu2;
    *(f16x4*)&nu1[off] = o_nu1;  *(f16x4*)&nu2[off] = o_nu2;

#pragma unroll
    for (int o = 32; o > 0; o >>= 1) {
      blp += __shfl_down(blp, o, 64);
      bup += __shfl_down(bup, o, 64);
    }
    if ((t & 63) == 0) { shmem[0][t >> 6] = blp; shmem[1][t >> 6] = bup; }
    __syncthreads();
    if (t == 0) {
      bl[i] += shmem[0][0] + shmem[0][1] + shmem[0][2] + shmem[0][3];
      bu[i] += shmem[1][0] + shmem[1][1] + shmem[1][2] + shmem[1][3];
    }
  } else {
    // ---------------- prep path (next layer's A) ----------------
    const int r = blockIdx.x - 1024;         // 0..511
    const int k0 = (r & 15) * 64;
    const int n0 = ((r >> 4) & 15) * 64;
    const int zz = r >> 8;                   // 0: lo, 1: up
    const int rid = t >> 4, cid = t & 15;
    const float* src = zz ? AupN : AloN;
    _Float16* d1 = zz ? U1 : L1;
    _Float16* d2 = zz ? U2 : L2;
#pragma unroll
    for (int rr = 0; rr < 4; ++rr) {
      const int kk = rid * 4 + rr;
      *(float4*)&shmem[kk][cid * 4] = *(const float4*)&src[(size_t)(k0 + kk) * DD + n0 + cid * 4];
    }
    __syncthreads();
#pragma unroll
    for (int rr = 0; rr < 4; ++rr) {
      const int n = rid * 4 + rr;
      f16x4 v1, v2;
#pragma unroll
      for (int e = 0; e < 4; ++e) {
        const float v = shmem[cid * 4 + e][n];
        const _Float16 h = (_Float16)v;
        v1[e] = h;
        v2[e] = (_Float16)((v - (float)h) * 2048.f);
      }
      const size_t o = (size_t)(n0 + n) * DD + k0 + cid * 4;
      *(f16x4*)&d1[o] = v1;
      *(f16x4*)&d2[o] = v2;
    }
  }
}

// -------- init: W -> W^T (fp32) --------
__global__ __launch_bounds__(256)
void transpose_w(const float* __restrict__ W, float* __restrict__ xt)
{
  __shared__ float tile[32][33];
  const int x  = blockIdx.x * 32 + threadIdx.x;
  const int y0 = blockIdx.y * 32 + threadIdx.y;
#pragma unroll
  for (int r = 0; r < 32; r += 8)
    tile[threadIdx.y + r][threadIdx.x] = W[(size_t)(y0 + r) * DD + x];
  __syncthreads();
  const int xo  = blockIdx.y * 32 + threadIdx.x;
  const int yo0 = blockIdx.x * 32 + threadIdx.y;
#pragma unroll
  for (int r = 0; r < 32; r += 8)
    xt[(size_t)(yo0 + r) * DD + xo] = tile[threadIdx.x][threadIdx.y + r];
}

// -------- final: reduce partials, concretize with input box --------
__global__ __launch_bounds__(256)
void bs_final2(const float* __restrict__ part,
               const float* __restrict__ bl, const float* __restrict__ bu,
               const float* __restrict__ inLo, const float* __restrict__ inUp,
               float* __restrict__ out)
{
  const int i = blockIdx.x;
  const int t = threadIdx.x;
  const int k = t * 4;
  const size_t off = (size_t)i * DD + k;
  float Xl[4] = {0.f, 0.f, 0.f, 0.f}, Xu[4] = {0.f, 0.f, 0.f, 0.f};
#pragma unroll
  for (int s = 0; s < 4; ++s) {
    const float4 a = *(const float4*)&part[((size_t)(s * 2 + 0) << 20) + off];
    const float4 b = *(const float4*)&part[((size_t)(s * 2 + 1) << 20) + off];
    Xl[0] += a.x; Xl[1] += a.y; Xl[2] += a.z; Xl[3] += a.w;
    Xu[0] += b.x; Xu[1] += b.y; Xu[2] += b.z; Xu[3] += b.w;
  }
  const float4 lo4 = *(const float4*)&inLo[k];
  const float4 up4 = *(const float4*)&inUp[k];
  const float Lo[4] = {lo4.x, lo4.y, lo4.z, lo4.w};
  const float Up[4] = {up4.x, up4.y, up4.z, up4.w};
  float sl = 0.f, su = 0.f;
#pragma unroll
  for (int e = 0; e < 4; ++e) {
    sl += fmaxf(Xl[e], 0.f) * Lo[e] + fminf(Xl[e], 0.f) * Up[e];
    su += fmaxf(Xu[e], 0.f) * Up[e] + fminf(Xu[e], 0.f) * Lo[e];
  }
#pragma unroll
  for (int o = 32; o > 0; o >>= 1) {
    sl += __shfl_down(sl, o, 64);
    su += __shfl_down(su, o, 64);
  }
  __shared__ float red[2][4];
  if ((t & 63) == 0) { red[0][t >> 6] = sl; red[1][t >> 6] = su; }
  __syncthreads();
  if (t == 0) {
    out[i]      = red[0][0] + red[0][1] + red[0][2] + red[0][3] + bl[i];
    out[DD + i] = red[1][0] + red[1][1] + red[1][2] + red[1][3] + bu[i];
  }
}

// ==================== fp32 fallback (round-1 baseline), used if ws too small ====================
#define BM 64
#define BN 64
#define BK 16
#define TM 4
#define TN 4
#define XPAD 4
#define XSTRIDE (BM + XPAD)

struct alignas(16) StepSmem {
  float xl[2][BK][XSTRIDE];
  float xu[2][BK][XSTRIDE];
  float alo[2][BK][BN];
  float aup[2][BK][BN];
  float clo[2][BK];
  float cup[2][BK];
  float bred[8][64];
};

__global__ __launch_bounds__(256)
void bs_step(const float* __restrict__ Xl, const float* __restrict__ Xu,
             float* __restrict__ Yl, float* __restrict__ Yu,
             const float* __restrict__ Alo, const float* __restrict__ Aup,
             const float* __restrict__ Clo, const float* __restrict__ Cup,
             float* __restrict__ bl, float* __restrict__ bu)
{
  __shared__ StepSmem sm;
  const int tid = threadIdx.x;
  const int tx = tid & 15;
  const int ty = tid >> 4;
  const int i0 = blockIdx.y * BM;
  const int j0 = blockIdx.x * BN;
  const bool doBias = (blockIdx.x == 0);
  const int xrow = tid >> 2;
  const int xseg = tid & 3;
  const int arow = tid >> 4;
  const int acol = (tid & 15) * 4;
  const int brow = tid & 63;
  const int bq   = tid >> 6;

  float accl[TM][TN] = {};
  float accu[TM][TN] = {};
  float blp = 0.f, bup = 0.f;
  float4 rxl, rxu, ral, rau;
  float  rc = 0.f;

  auto load_panel = [&](int kp) {
    rxl = *(const float4*)&Xl[(size_t)(i0 + xrow) * DD + kp + xseg * 4];
    rxu = *(const float4*)&Xu[(size_t)(i0 + xrow) * DD + kp + xseg * 4];
    ral = *(const float4*)&Alo[(size_t)(kp + arow) * DD + j0 + acol];
    rau = *(const float4*)&Aup[(size_t)(kp + arow) * DD + j0 + acol];
    if (tid < 32) rc = (tid < 16) ? Clo[kp + tid] : Cup[kp + tid - 16];
  };
  auto store_panel = [&](int b) {
    const float* pxl = (const float*)&rxl;
    const float* pxu = (const float*)&rxu;
#pragma unroll
    for (int s2 = 0; s2 < 4; ++s2) {
      sm.xl[b][xseg * 4 + s2][xrow] = pxl[s2];
      sm.xu[b][xseg * 4 + s2][xrow] = pxu[s2];
    }
    *(float4*)&sm.alo[b][arow][acol] = ral;
    *(float4*)&sm.aup[b][arow][acol] = rau;
    if (tid < 16)      sm.clo[b][tid] = rc;
    else if (tid < 32) sm.cup[b][tid - 16] = rc;
  };

  load_panel(0);
  store_panel(0);
  __syncthreads();

  constexpr int NP = DD / BK;
  for (int p = 0; p < NP; ++p) {
    const int buf = p & 1;
    const bool more = (p + 1 < NP);
    if (more) load_panel((p + 1) * BK);
#pragma unroll 4
    for (int k = 0; k < BK; ++k) {
      const float4 xl4 = *(const float4*)&sm.xl[buf][k][ty * TM];
      const float4 xu4 = *(const float4*)&sm.xu[buf][k][ty * TM];
      const float4 al4 = *(const float4*)&sm.alo[buf][k][tx * TN];
      const float4 au4 = *(const float4*)&sm.aup[buf][k][tx * TN];
      const float xlv[TM] = {xl4.x, xl4.y, xl4.z, xl4.w};
      const float xuv[TM] = {xu4.x, xu4.y, xu4.z, xu4.w};
      const float alv[TN] = {al4.x, al4.y, al4.z, al4.w};
      const float auv[TN] = {au4.x, au4.y, au4.z, au4.w};
#pragma unroll
      for (int m = 0; m < TM; ++m) {
        const float pl = fmaxf(xlv[m], 0.f), nl = fminf(xlv[m], 0.f);
        const float pu = fmaxf(xuv[m], 0.f), nu = fminf(xuv[m], 0.f);
#pragma unroll
        for (int n = 0; n < TN; ++n) {
          accl[m][n] = fmaf(pl, alv[n], fmaf(nl, auv[n], accl[m][n]));
          accu[m][n] = fmaf(pu, auv[n], fmaf(nu, alv[n], accu[m][n]));
        }
      }
    }
    if (doBias) {
#pragma unroll
      for (int kk = 0; kk < 4; ++kk) {
        const int k = bq * 4 + kk;
        const float xlv = sm.xl[buf][k][brow];
        const float xuv = sm.xu[buf][k][brow];
        const float cl = sm.clo[buf][k], cu = sm.cup[buf][k];
        blp += fmaxf(xlv, 0.f) * cl + fminf(xlv, 0.f) * cu;
        bup += fmaxf(xuv, 0.f) * cu + fminf(xuv, 0.f) * cl;
      }
    }
    if (more) store_panel(buf ^ 1);
    __syncthreads();
  }

#pragma unroll
  for (int m = 0; m < TM; ++m) {
    *(float4*)&Yl[(size_t)(i0 + ty * TM + m) * DD + j0 + tx * TN] =
        make_float4(accl[m][0], accl[m][1], accl[m][2], accl[m][3]);
    *(float4*)&Yu[(size_t)(i0 + ty * TM + m) * DD + j0 + tx * TN] =
        make_float4(accu[m][0], accu[m][1], accu[m][2], accu[m][3]);
  }
  if (doBias) {
    sm.bred[bq][brow]     = blp;
    sm.bred[4 + bq][brow] = bup;
    __syncthreads();
    if (tid < 64) {
      const int i = i0 + tid;
      bl[i] += sm.bred[0][tid] + sm.bred[1][tid] + sm.bred[2][tid] + sm.bred[3][tid];
      bu[i] += sm.bred[4][tid] + sm.bred[5][tid] + sm.bred[6][tid] + sm.bred[7][tid];
    }
  }
}

__global__ __launch_bounds__(256)
void bs_transpose_init(const float* __restrict__ W,
                       float* __restrict__ xl, float* __restrict__ xu)
{
  __shared__ float tile[32][33];
  const int x  = blockIdx.x * 32 + threadIdx.x;
  const int y0 = blockIdx.y * 32 + threadIdx.y;
#pragma unroll
  for (int r = 0; r < 32; r += 8)
    tile[threadIdx.y + r][threadIdx.x] = W[(size_t)(y0 + r) * DD + x];
  __syncthreads();
  const int xo  = blockIdx.y * 32 + threadIdx.x;
  const int yo0 = blockIdx.x * 32 + threadIdx.y;
#pragma unroll
  for (int r = 0; r < 32; r += 8) {
    const float v = tile[threadIdx.x][threadIdx.y + r];
    xl[(size_t)(yo0 + r) * DD + xo] = v;
    xu[(size_t)(yo0 + r) * DD + xo] = v;
  }
}

__global__ __launch_bounds__(256)
void bs_final(const float* __restrict__ Xl, const float* __restrict__ Xu,
              const float* __restrict__ bl, const float* __restrict__ bu,
              const float* __restrict__ inLo, const float* __restrict__ inUp,
              float* __restrict__ out)
{
  __shared__ float red[2][4];
  const int i = blockIdx.x;
  const int tid = threadIdx.x;
  const float4 xl4 = *(const float4*)&Xl[(size_t)i * DD + tid * 4];
  const float4 xu4 = *(const float4*)&Xu[(size_t)i * DD + tid * 4];
  const float4 lo4 = *(const float4*)&inLo[tid * 4];
  const float4 up4 = *(const float4*)&inUp[tid * 4];
  const float xlv[4] = {xl4.x, xl4.y, xl4.z, xl4.w};
  const float xuv[4] = {xu4.x, xu4.y, xu4.z, xu4.w};
  const float lov[4] = {lo4.x, lo4.y, lo4.z, lo4.w};
  const float upv[4] = {up4.x, up4.y, up4.z, up4.w};
  float sl = 0.f, su = 0.f;
#pragma unroll
  for (int c = 0; c < 4; ++c) {
    sl += fmaxf(xlv[c], 0.f) * lov[c] + fminf(xlv[c], 0.f) * upv[c];
    su += fmaxf(xuv[c], 0.f) * upv[c] + fminf(xuv[c], 0.f) * lov[c];
  }
#pragma unroll
  for (int off = 32; off > 0; off >>= 1) {
    sl += __shfl_down(sl, off, 64);
    su += __shfl_down(su, off, 64);
  }
  if ((tid & 63) == 0) { red[0][tid >> 6] = sl; red[1][tid >> 6] = su; }
  __syncthreads();
  if (tid == 0) {
    out[i]      = red[0][0] + red[0][1] + red[0][2] + red[0][3] + bl[i];
    out[DD + i] = red[1][0] + red[1][1] + red[1][2] + red[1][3] + bu[i];
  }
}

// ==================== host ====================
extern "C" void kernel_launch(void* const* d_in, const int* in_sizes, int n_in,
                              void* d_out, int out_size, void* d_ws, size_t ws_size,
                              hipStream_t stream)
{
  const float* W      = (const float*)d_in[0];
  const float* biases = (const float*)d_in[1];
  const float* AloAll = (const float*)d_in[2];
  const float* AupAll = (const float*)d_in[3];
  const float* CloAll = (const float*)d_in[4];
  const float* CupAll = (const float*)d_in[5];
  const float* inLo   = (const float*)d_in[6];
  const float* inUp   = (const float*)d_in[7];
  float* out = (float*)d_out;

  const size_t NEED = (60ull << 20) + 8192;
  if (ws_size < NEED) {
    // ---------- fp32 fallback (round-1) ----------
    float* ws  = (float*)d_ws;
    float* XA  = ws;
    float* XuA = ws + (size_t)DD * DD;
    float* XB  = ws + 2ull * DD * DD;
    float* XuB = ws + 3ull * DD * DD;
    float* bl  = ws + 4ull * DD * DD;
    float* bu  = bl + DD;
    bs_transpose_init<<<dim3(DD / 32, DD / 32), dim3(32, 8), 0, stream>>>(W, XA, XuA);
    hipMemcpyAsync(bl, biases, DD * sizeof(float), hipMemcpyDeviceToDevice, stream);
    hipMemcpyAsync(bu, biases, DD * sizeof(float), hipMemcpyDeviceToDevice, stream);
    const float* xi  = XA;  const float* xui = XuA;
    float*       xo  = XB;  float*       xuo = XuB;
    for (int l = 0; l < LL; ++l) {
      bs_step<<<dim3(DD / BN, DD / BM), 256, 0, stream>>>(
          xi, xui, xo, xuo,
          AloAll + (size_t)l * DD * DD, AupAll + (size_t)l * DD * DD,
          CloAll + (size_t)l * DD,      CupAll + (size_t)l * DD, bl, bu);
      const float* txi = xi; const float* txui = xui;
      xi = xo; xui = xuo;
      xo = (float*)txi; xuo = (float*)txui;
    }
    bs_final<<<DD, 256, 0, stream>>>(xi, xui, bl, bu, inLo, inUp, out);
    return;
  }

  // ---------- f16-split MFMA path ----------
  char* ws = (char*)d_ws;
  float*     part = (float*)ws;                          // 8 slabs x 4 MB = 32 MB
  _Float16*  xpl  = (_Float16*)(ws + (32ull << 20));     // 8 X planes x 2 MB
  _Float16*  apl  = (_Float16*)(ws + (48ull << 20));     // 4 A planes x 2 MB
  float*     XT   = (float*)(ws + (56ull << 20));        // 4 MB
  float*     bl   = (float*)(ws + (60ull << 20));
  float*     bu   = bl + DD;

  auto P = [&](int idx) { return xpl + (size_t)idx * (1u << 20); };
  _Float16 *pl1 = P(0), *pl2 = P(1), *nl1 = P(2), *nl2 = P(3);
  _Float16 *pu1 = P(4), *pu2 = P(5), *nu1 = P(6), *nu2 = P(7);
  _Float16 *AL1 = apl, *AL2 = apl + (1u << 20), *AU1 = apl + (2u << 20), *AU2 = apl + (3u << 20);

  GemmTabs tabs;
  // lu=0 (xl'): scaled group first: pl1*AL2', pl2'*AL1, nl1*AU2', nl2'*AU1 ; then pl1*AL1, nl1*AU1
  const _Float16* xs0[6] = {pl1, pl2, nl1, nl2, pl1, nl1};
  const _Float16* as0[6] = {AL2, AL1, AU2, AU1, AL1, AU1};
  // lu=1 (xu'): pu1*AU2', pu2'*AU1, nu1*AL2', nu2'*AL1 ; then pu1*AU1, nu1*AL1
  const _Float16* xs1[6] = {pu1, pu2, nu1, nu2, pu1, nu1};
  const _Float16* as1[6] = {AU2, AU1, AL2, AL1, AU1, AL1};
  for (int s = 0; s < 6; ++s) {
    tabs.xs[0][s] = xs0[s]; tabs.as[0][s] = as0[s];
    tabs.xs[1][s] = xs1[s]; tabs.as[1][s] = as1[s];
  }

  transpose_w<<<dim3(32, 32), dim3(32, 8), 0, stream>>>(W, XT);
  hipMemcpyAsync(bl, biases, DD * sizeof(float), hipMemcpyDeviceToDevice, stream);
  hipMemcpyAsync(bu, biases, DD * sizeof(float), hipMemcpyDeviceToDevice, stream);

  // initial: direct convert of W^T + prep layer 0's A planes
  convert_prep<<<1536, 256, 0, stream>>>(1, XT, part, CloAll, CupAll,
                                         pl1, pl2, nl1, nl2, pu1, pu2, nu1, nu2, bl, bu,
                                         AloAll, AupAll, AL1, AL2, AU1, AU2);
  for (int s = 0; s < LL; ++s) {
    gemm_step<<<dim3(8, 8, 8), 256, 0, stream>>>(tabs, part);
    if (s < LL - 1)
      convert_prep<<<1536, 256, 0, stream>>>(0, XT, part,
                                             CloAll + (size_t)(s + 1) * DD,
                                             CupAll + (size_t)(s + 1) * DD,
                                             pl1, pl2, nl1, nl2, pu1, pu2, nu1, nu2, bl, bu,
                                             AloAll + (size_t)(s + 1) * DD * DD,
                                             AupAll + (size_t)(s + 1) * DD * DD,
                                             AL1, AL2, AU1, AU2);
  }
  bs_final2<<<DD, 256, 0, stream>>>(part, bl, bu, inLo, inUp, out);
}